// Round 1
// baseline (5074.273 us; speedup 1.0000x reference)
//
#include <hip/hip_runtime.h>

typedef short s16x8 __attribute__((ext_vector_type(8)));
typedef float f32x4 __attribute__((ext_vector_type(4)));

static __device__ __forceinline__ unsigned short f2bf(float f){
  unsigned u = __builtin_bit_cast(unsigned, f);
  unsigned r = (u + 0x7fffu + ((u >> 16) & 1u)) >> 16;
  return (unsigned short)r;
}
static __device__ __forceinline__ float sigm(float x){
  return __builtin_amdgcn_rcpf(1.f + __expf(-x));
}
static __device__ __forceinline__ float tanh_(float x){
  float e = __expf(2.f * x);
  return 1.f - 2.f * __builtin_amdgcn_rcpf(e + 1.f);
}

// ---------------- generic transpose: out[c*R + r] = in[r*ld + c] ----------------
__global__ void k_tr(const float* __restrict__ in, float* __restrict__ out, int R, int C, int ld){
  int i = blockIdx.x * 256 + threadIdx.x;
  if (i >= R * C) return;
  int c = i / R, r = i - c * R;
  out[i] = in[r * ld + c];
}

// ---------------- pack W_out into MFMA-B-fragment order, bf16 ----------------
// Wb[((nt*8+ks)*64+l)*8+j] = W[nt*16+(l&15)][ks*32+(l>>4)*8+j]
__global__ void k_wbpack(const float* __restrict__ W, unsigned short* __restrict__ Wb){
  int p = blockIdx.x * 256 + threadIdx.x;   // 8,192,000 total
  int j = p & 7, l = (p >> 3) & 63, ks = (p >> 9) & 7, nt = p >> 12;
  int v = nt * 16 + (l & 15);
  int k = ks * 32 + ((l >> 4) << 3) + j;
  Wb[p] = f2bf(W[v * 256 + k]);
}

// ---------------- UaK[b,s,h] = keys[b,s,:] @ Ua.T + bUa ----------------
__global__ void k_uak(const float* __restrict__ keys, const float* __restrict__ UaT,
                      const float* __restrict__ bUa, float* __restrict__ UaK){
  __shared__ float kl[256];
  int row = blockIdx.x, tid = threadIdx.x;      // row = b*64+s
  kl[tid] = keys[row * 256 + tid];
  __syncthreads();
  float acc = bUa[tid];
  #pragma unroll 8
  for (int k = 0; k < 256; ++k) acc += kl[k] * UaT[k * 256 + tid];
  UaK[row * 256 + tid] = acc;
}

// ---------------- giE[t,b,:] = emb(tok) @ W_ih0[:, :256].T + b_ih[0] ----------------
__global__ void k_gie(const int* __restrict__ tok, const float* __restrict__ emb,
                      const float* __restrict__ W0eT, const float* __restrict__ bih,
                      float* __restrict__ giE){
  __shared__ float el[256];
  int blk = blockIdx.x;                 // blk = t*32 + b
  int t = blk >> 5, b = blk & 31, tid = threadIdx.x;
  int tk = tok[b * 64 + t];
  el[tid] = emb[tk * 256 + tid];
  __syncthreads();
  for (int g = tid; g < 768; g += 256){
    float acc = bih[g];
    #pragma unroll 8
    for (int k = 0; k < 256; ++k) acc += el[k] * W0eT[k * 768 + g];
    giE[blk * 768 + g] = acc;
  }
}

// ---------------- sequential recurrence: one block per batch element ----------------
__launch_bounds__(512)
__global__ void k_seq(const float* __restrict__ keys, const float* __restrict__ ehid,
                      const float* __restrict__ WaT, const float* __restrict__ bWa,
                      const float* __restrict__ Va, const float* __restrict__ bVa,
                      const float* __restrict__ UaK, const float* __restrict__ giE,
                      const float* __restrict__ W0cT, const float* __restrict__ WihT,
                      const float* __restrict__ WhhT, const float* __restrict__ bih,
                      const float* __restrict__ bhh,
                      unsigned short* __restrict__ Xb, float* __restrict__ outH,
                      float* __restrict__ outA)
{
  __shared__ float h[1024];      // [l][256] == query layout
  __shared__ float vlds[256];
  __shared__ float qWp[1024];
  __shared__ float qW[256];
  __shared__ float ghA[3072];    // [l][768]
  __shared__ float sc[64];
  __shared__ float watt[64];
  __shared__ float ctx[256];
  __shared__ float gi[768];
  __shared__ float red[1536];
  const int b = blockIdx.x;
  const int tid = threadIdx.x;

  for (int i = tid; i < 1024; i += 512) h[i] = ehid[(i >> 8) * 8192 + b * 256 + (i & 255)];
  if (tid < 256) vlds[tid] = Va[tid];
  __syncthreads();

  for (int t = 0; t < 64; ++t){
    // ---- Phase 1: qW partials (4 l-chunks of K) + gh for all 4 layers, from prev-step h
    #pragma unroll
    for (int pass = 0; pass < 2; ++pass){
      const int gidx = tid + pass * 512;
      const float* wp; int wstride, l, oo, isq;
      if (gidx < 256){
        isq = 1; l = gidx >> 6; oo = (gidx & 63) * 4;
        wp = WaT + l * 65536 + oo; wstride = 256;
      } else {
        isq = 0; int gid = gidx - 256; l = gid / 192; oo = (gid - l * 192) * 4;
        wp = WhhT + l * 196608 + oo; wstride = 768;
      }
      const float* xv = h + l * 256;
      float ax = 0.f, ay = 0.f, az = 0.f, aw = 0.f;
      #pragma unroll 8
      for (int k = 0; k < 256; ++k){
        float x = xv[k];
        float4 w = *(const float4*)(wp);
        ax += x * w.x; ay += x * w.y; az += x * w.z; aw += x * w.w;
        wp += wstride;
      }
      if (isq){
        float* d = qWp + l * 256 + oo;
        d[0] = ax; d[1] = ay; d[2] = az; d[3] = aw;
      } else {
        const float* bb = bhh + l * 768 + oo;
        float* d = ghA + l * 768 + oo;
        d[0] = ax + bb[0]; d[1] = ay + bb[1]; d[2] = az + bb[2]; d[3] = aw + bb[3];
      }
    }
    __syncthreads();
    if (tid < 256) qW[tid] = qWp[tid] + qWp[256 + tid] + qWp[512 + tid] + qWp[768 + tid] + bWa[tid];
    __syncthreads();

    // ---- Phase 2: scores[s] = Va . tanh(qW + UaK[b,s,:]) + bVa
    {
      int s = tid >> 3, p = tid & 7;
      const float* up = UaK + ((b << 6) + s) * 256 + p * 32;
      const float* qp = qW + p * 32;
      const float* vp = vlds + p * 32;
      float acc = 0.f;
      #pragma unroll 8
      for (int i = 0; i < 32; ++i){
        float e = tanh_(qp[i] + up[i]);
        acc += vp[i] * e;
      }
      acc += __shfl_xor(acc, 1, 64);
      acc += __shfl_xor(acc, 2, 64);
      acc += __shfl_xor(acc, 4, 64);
      if (p == 0) sc[s] = acc + bVa[0];
    }
    __syncthreads();

    // ---- Phase 3: softmax over S=64 (wave 0)
    if (tid < 64){
      float v = sc[tid];
      float m = v;
      #pragma unroll
      for (int off = 1; off < 64; off <<= 1) m = fmaxf(m, __shfl_xor(m, off, 64));
      float e = __expf(v - m);
      float ssum = e;
      #pragma unroll
      for (int off = 1; off < 64; off <<= 1) ssum += __shfl_xor(ssum, off, 64);
      float w = e * __builtin_amdgcn_rcpf(ssum);
      watt[tid] = w;
      outA[(b * 64 + t) * 64 + tid] = w;
    }
    __syncthreads();

    // ---- Phase 4: ctx = w @ keys[b]
    {
      int o = tid & 255, p = tid >> 8;
      const float* kp = keys + (b * 64 + p * 32) * 256 + o;
      float acc = 0.f;
      #pragma unroll 8
      for (int s2 = 0; s2 < 32; ++s2) acc += watt[p * 32 + s2] * kp[s2 * 256];
      red[tid] = acc;
    }
    __syncthreads();
    if (tid < 256) ctx[tid] = red[tid] + red[256 + tid];
    __syncthreads();

    // ---- Phases 5..8: GRU layers
    const float* giB = giE + (t * 32 + b) * 768;
    for (int l = 0; l < 4; ++l){
      const float* xv = (l == 0) ? ctx : (h + (l - 1) * 256);
      const float* wb = (l == 0) ? W0cT : (WihT + (l - 1) * 196608);
      if (tid < 384){
        int oo = (tid % 192) * 4, kp2 = tid / 192;
        const float* wp = wb + (kp2 * 128) * 768 + oo;
        const float* xp = xv + kp2 * 128;
        float ax = 0.f, ay = 0.f, az = 0.f, aw = 0.f;
        #pragma unroll 8
        for (int k = 0; k < 128; ++k){
          float x = xp[k];
          float4 w = *(const float4*)(wp);
          ax += x * w.x; ay += x * w.y; az += x * w.z; aw += x * w.w;
          wp += 768;
        }
        float* d = red + kp2 * 768 + oo;
        d[0] = ax; d[1] = ay; d[2] = az; d[3] = aw;
      }
      __syncthreads();
      for (int o = tid; o < 768; o += 512){
        float base = (l == 0) ? giB[o] : bih[l * 768 + o];
        gi[o] = base + red[o] + red[768 + o];
      }
      __syncthreads();
      if (tid < 256){
        int o = tid;
        const float* gh = ghA + l * 768;
        float r = sigm(gi[o] + gh[o]);
        float z = sigm(gi[256 + o] + gh[256 + o]);
        float n = tanh_(gi[512 + o] + r * gh[512 + o]);
        float hold = h[l * 256 + o];
        float hn = (1.f - z) * n + z * hold;
        h[l * 256 + o] = hn;
        if (l == 3) Xb[(b * 64 + t) * 256 + o] = f2bf(hn);
      }
      __syncthreads();
    }
  }
  for (int i = tid; i < 1024; i += 512) outH[(i >> 8) * 8192 + b * 256 + (i & 255)] = h[i];
}

// ---------------- logits pass 1: per-row sum(exp(logit)) partials ----------------
__launch_bounds__(512)
__global__ void k_g1(const unsigned short* __restrict__ Xb, const unsigned short* __restrict__ Wb,
                     const float* __restrict__ bout, float* __restrict__ Spart)
{
  const int mt = blockIdx.x, nc = blockIdx.y;
  const int tid = threadIdx.x, lane = tid & 63, wv = tid >> 6;
  const int c = lane & 15, q = lane >> 4;
  const int r0 = mt * 64;
  s16x8 afr[4][8];
  #pragma unroll
  for (int rt = 0; rt < 4; ++rt){
    const unsigned short* xp = Xb + (r0 + rt * 16 + c) * 256 + q * 8;
    #pragma unroll
    for (int ks = 0; ks < 8; ++ks) afr[rt][ks] = *(const s16x8*)(xp + ks * 32);
  }
  float ssum[4][4];
  #pragma unroll
  for (int rt = 0; rt < 4; ++rt){ ssum[rt][0]=0.f; ssum[rt][1]=0.f; ssum[rt][2]=0.f; ssum[rt][3]=0.f; }
  const int ntEnd = nc * 250 + 250;
  for (int nt = nc * 250 + wv; nt < ntEnd; nt += 8){
    const unsigned short* wp = Wb + nt * 4096 + lane * 8;
    f32x4 acc[4];
    #pragma unroll
    for (int rt = 0; rt < 4; ++rt) acc[rt] = (f32x4){0.f, 0.f, 0.f, 0.f};
    #pragma unroll
    for (int ks = 0; ks < 8; ++ks){
      s16x8 bfr = *(const s16x8*)(wp + ks * 512);
      #pragma unroll
      for (int rt = 0; rt < 4; ++rt)
        acc[rt] = __builtin_amdgcn_mfma_f32_16x16x32_bf16(afr[rt][ks], bfr, acc[rt], 0, 0, 0);
    }
    float bo = bout[nt * 16 + c];
    #pragma unroll
    for (int rt = 0; rt < 4; ++rt){
      #pragma unroll
      for (int i = 0; i < 4; ++i) ssum[rt][i] += __expf(acc[rt][i] + bo);
    }
  }
  #pragma unroll
  for (int off = 1; off < 16; off <<= 1){
    #pragma unroll
    for (int rt = 0; rt < 4; ++rt){
      #pragma unroll
      for (int i = 0; i < 4; ++i) ssum[rt][i] += __shfl_xor(ssum[rt][i], off, 64);
    }
  }
  __shared__ float lred[8][64];
  if (c == 0){
    #pragma unroll
    for (int rt = 0; rt < 4; ++rt){
      #pragma unroll
      for (int i = 0; i < 4; ++i) lred[wv][rt * 16 + q * 4 + i] = ssum[rt][i];
    }
  }
  __syncthreads();
  if (tid < 64){
    float s = 0.f;
    #pragma unroll
    for (int w = 0; w < 8; ++w) s += lred[w][tid];
    Spart[(r0 + tid) * 8 + nc] = s;
  }
}

__global__ void k_g1b(const float* __restrict__ Spart, float* __restrict__ Z){
  int r = blockIdx.x * 256 + threadIdx.x;
  float s = 0.f;
  #pragma unroll
  for (int nc = 0; nc < 8; ++nc) s += Spart[r * 8 + nc];
  Z[r] = __logf(s);
}

// ---------------- logits pass 2: recompute, write log_softmax ----------------
__launch_bounds__(512)
__global__ void k_g2(const unsigned short* __restrict__ Xb, const unsigned short* __restrict__ Wb,
                     const float* __restrict__ bout, const float* __restrict__ Z,
                     float* __restrict__ out)
{
  const int mt = blockIdx.x, nc = blockIdx.y;
  const int tid = threadIdx.x, lane = tid & 63, wv = tid >> 6;
  const int c = lane & 15, q = lane >> 4;
  const int r0 = mt * 64;
  s16x8 afr[4][8];
  #pragma unroll
  for (int rt = 0; rt < 4; ++rt){
    const unsigned short* xp = Xb + (r0 + rt * 16 + c) * 256 + q * 8;
    #pragma unroll
    for (int ks = 0; ks < 8; ++ks) afr[rt][ks] = *(const s16x8*)(xp + ks * 32);
  }
  float zr[4][4];
  #pragma unroll
  for (int rt = 0; rt < 4; ++rt){
    #pragma unroll
    for (int i = 0; i < 4; ++i) zr[rt][i] = Z[r0 + rt * 16 + q * 4 + i];
  }
  const int ntEnd = nc * 250 + 250;
  for (int nt = nc * 250 + wv; nt < ntEnd; nt += 8){
    const unsigned short* wp = Wb + nt * 4096 + lane * 8;
    f32x4 acc[4];
    #pragma unroll
    for (int rt = 0; rt < 4; ++rt) acc[rt] = (f32x4){0.f, 0.f, 0.f, 0.f};
    #pragma unroll
    for (int ks = 0; ks < 8; ++ks){
      s16x8 bfr = *(const s16x8*)(wp + ks * 512);
      #pragma unroll
      for (int rt = 0; rt < 4; ++rt)
        acc[rt] = __builtin_amdgcn_mfma_f32_16x16x32_bf16(afr[rt][ks], bfr, acc[rt], 0, 0, 0);
    }
    float bo = bout[nt * 16 + c];
    #pragma unroll
    for (int rt = 0; rt < 4; ++rt){
      #pragma unroll
      for (int i = 0; i < 4; ++i)
        out[(r0 + rt * 16 + q * 4 + i) * 32000 + nt * 16 + c] = acc[rt][i] + bo - zr[rt][i];
    }
  }
}

extern "C" void kernel_launch(void* const* d_in, const int* in_sizes, int n_in,
                              void* d_out, int out_size, void* d_ws, size_t ws_size,
                              hipStream_t stream)
{
  const float* keys = (const float*)d_in[0];
  const float* ehid = (const float*)d_in[1];
  const int*   dinp = (const int*)d_in[2];
  const float* emb  = (const float*)d_in[3];
  const float* Wa   = (const float*)d_in[4];
  const float* bWa  = (const float*)d_in[5];
  const float* Ua   = (const float*)d_in[6];
  const float* bUa  = (const float*)d_in[7];
  const float* Va   = (const float*)d_in[8];
  const float* bVa  = (const float*)d_in[9];
  const float* Wih0 = (const float*)d_in[10];
  const float* Wihr = (const float*)d_in[11];
  const float* Whh  = (const float*)d_in[12];
  const float* bih  = (const float*)d_in[13];
  const float* bhh  = (const float*)d_in[14];
  const float* Wout = (const float*)d_in[15];
  const float* bout = (const float*)d_in[16];

  char* ws = (char*)d_ws;
  float* WaT   = (float*)(ws + 0);          // 1 MB
  float* UaT   = (float*)(ws + 1048576);    // 256 KB
  float* W0eT  = (float*)(ws + 1310720);    // 768 KB
  float* W0cT  = (float*)(ws + 2097152);    // 768 KB
  float* WihT  = (float*)(ws + 2883584);    // 2.25 MB
  float* WhhT  = (float*)(ws + 5242880);    // 3 MB
  float* UaK   = (float*)(ws + 8388608);    // 2 MB
  float* giE   = (float*)(ws + 10485760);   // 6 MB
  unsigned short* Xb = (unsigned short*)(ws + 16777216);  // 1 MB
  unsigned short* Wb = (unsigned short*)(ws + 17825792);  // 16.384 MB
  float* Spart = (float*)(ws + 34209792);   // 64 KB
  float* Zr    = (float*)(ws + 34275328);   // 8 KB

  float* outL = (float*)d_out;
  float* outH = outL + 65536000;
  float* outA = outH + 32768;

  // weight transposes
  k_tr<<<1024, 256, 0, stream>>>(Wa,   WaT,  256, 1024, 1024);
  k_tr<<<256,  256, 0, stream>>>(Ua,   UaT,  256, 256,  256);
  k_tr<<<768,  256, 0, stream>>>(Wih0,       W0eT, 768, 256, 512);
  k_tr<<<768,  256, 0, stream>>>(Wih0 + 256, W0cT, 768, 256, 512);
  for (int l = 0; l < 3; ++l)
    k_tr<<<768, 256, 0, stream>>>(Wihr + l * 196608, WihT + l * 196608, 768, 256, 256);
  for (int l = 0; l < 4; ++l)
    k_tr<<<768, 256, 0, stream>>>(Whh + l * 196608, WhhT + l * 196608, 768, 256, 256);

  k_wbpack<<<32000, 256, 0, stream>>>(Wout, Wb);
  k_uak<<<2048, 256, 0, stream>>>(keys, UaT, bUa, UaK);
  k_gie<<<2048, 256, 0, stream>>>(dinp, emb, W0eT, bih, giE);

  k_seq<<<32, 512, 0, stream>>>(keys, ehid, WaT, bWa, Va, bVa, UaK, giE,
                                W0cT, WihT, WhhT, bih, bhh, Xb, outH, outA);

  k_g1<<<dim3(32, 8), 512, 0, stream>>>(Xb, Wb, bout, Spart);
  k_g1b<<<8, 256, 0, stream>>>(Spart, Zr);
  k_g2<<<dim3(32, 8), 512, 0, stream>>>(Xb, Wb, bout, Zr, outL);
}